// Round 15
// baseline (266.661 us; speedup 1.0000x reference)
//
#include <hip/hip_runtime.h>
#include <hip/hip_bf16.h>
#include <math.h>

#define SEQ_LEN 128
#define BATCH   32
#define T       32
#define TT      (T*T)     // 1024
#define TTT     (T*T*T)   // 32768
#define START   30
#define END     31
#define NHOP    32

#define LOG2E   1.44269504088896f
#define OFF4    5.77078016355587f   // 4 * log2(e)

typedef unsigned long long u64;

__device__ __forceinline__ u64 pt_pack(int tag, float v) {
    union { float f; unsigned int u; } c; c.f = v;
    return ((u64)(unsigned int)tag << 32) | (u64)c.u;
}
__device__ __forceinline__ float pt_val(u64 w) {
    union { unsigned int u; float f; } c; c.u = (unsigned int)w; return c.f;
}
__device__ __forceinline__ int pt_tag(u64 w) { return (int)(w >> 32); }

__device__ __forceinline__ u64 ald64(const u64* p) {
    return __hip_atomic_load(p, __ATOMIC_RELAXED, __HIP_MEMORY_SCOPE_AGENT);
}
__device__ __forceinline__ void ast64(u64* p, u64 v) {
    __hip_atomic_store(p, v, __ATOMIC_RELAXED, __HIP_MEMORY_SCOPE_AGENT);
}

// raw barrier: drain LDS ops only; global prefetch/publish stay in flight
#define BLOCK_SYNC() do {                                   \
    asm volatile("s_waitcnt lgkmcnt(0)" ::: "memory");      \
    __builtin_amdgcn_sched_barrier(0);                      \
    __builtin_amdgcn_s_barrier();                           \
    __builtin_amdgcn_sched_barrier(0);                      \
} while (0)

// ---------------------------------------------------------------------------
// Kernel 1: tg_energy gather. ws[0..15] <- per-block partial sums.
// ---------------------------------------------------------------------------
__global__ __launch_bounds__(256) void tg_kernel(const float* __restrict__ scores,
                                                 const int*   __restrict__ target,
                                                 const int*   __restrict__ mask,
                                                 float*       __restrict__ ws) {
    int idx = blockIdx.x * 256 + threadIdx.x;
    float v = 0.0f;
    if (mask[idx] != 0) v = scores[(size_t)idx * TTT + target[idx]];
    #pragma unroll
    for (int off = 32; off > 0; off >>= 1) v += __shfl_down(v, off, 64);
    __shared__ float partial[4];
    int wave = threadIdx.x >> 6, lane = threadIdx.x & 63;
    if (lane == 0) partial[wave] = v;
    __syncthreads();
    if (threadIdx.x == 0)
        ws[blockIdx.x] = partial[0] + partial[1] + partial[2] + partial[3];
}

// ---------------------------------------------------------------------------
// Kernel 2: init. Both states FIRST-MAJOR [u*32+v]. parity0 <- tag 0 state;
// parity1 <- 0 (replay-safe full overwrite).
// fwd: Q_1[i,j] = exp(p1[i] + s1[i,j]). bwd: R_127 = indicator(END,END).
// ---------------------------------------------------------------------------
__global__ __launch_bounds__(256) void init_pf(const float* __restrict__ scores,
                                               u64* __restrict__ ptF,
                                               u64* __restrict__ ptB) {
    const int blk = blockIdx.x, tid = threadIdx.x;
    if (blk < BATCH) {
        const int b = blk;
        u64* pt = ptF + (size_t)b * 2048;
        #pragma unroll
        for (int q = 0; q < 4; ++q) {
            int e = q * 256 + tid;           // e = i*32 + j (first-major)
            int i = e >> 5, j = e & 31;
            float p1 = scores[(size_t)(0*BATCH + b)*TTT + START*TT + START*T + i];
            float s1 = scores[(size_t)(1*BATCH + b)*TTT + START*TT + i*T + j];
            pt[e]        = pt_pack(0, __expf(p1 + s1));
            pt[1024 + e] = 0ULL;
        }
    } else {
        const int b = blk - BATCH;
        u64* pt = ptB + (size_t)b * 2048;
        #pragma unroll
        for (int q = 0; q < 4; ++q) {
            int e = q * 256 + tid;
            pt[e]        = pt_pack(0, (e == END*T + END) ? 1.0f : 0.0f);
            pt[1024 + e] = 0ULL;
        }
    }
}

// ---------------------------------------------------------------------------
// Kernel 3: pair-fused distributed fwd/bwd scan. 512 blocks x 512 threads,
// 2 blocks/CU co-resident. g=bid&7, chain=bid>>3, b=chain&31, dirB=chain>=32.
// 32 hops per direction; hop = 2 steps (1 exchange), last hop = 1 step.
// State: FIRST-MAJOR [u*32+v], tagged u64, 2 parity buffers; hop p consumes
// tag p (parity p&1), publishes tag p+1 (parity (p+1)&1). Every thread polls
// 2 words (full 1024-word state) BEFORE B1; all publishes after B1 => the
// r8 certification induction holds unchanged.
//  FWD hop (t0,t1): block g owns output k in Kg=[4g,4g+4):
//    phase1 I[j,k] = sum_i E_t0[i,j,k] Q[i,j]   (E0 strided f4, staged->LDS)
//    phase2 O[k,l] = sum_j E_t1[j,k,l] I[j,k]   (E1 contiguous runs, regs)
//  BWD hop (th,tl=th-1): block g owns output i in Ig:
//    phase1 I[i,j] = sum_k E_th[i,j,k] V[j,k]   (contiguous, regs)
//    phase2 W[h,i] = sum_j E_tl[h,i,j] I[i,j]   (128B chunks, regs)
// exp2(x*log2e - 4log2e) applied per MAC; masked modes: 1=single step (tA),
// 0=copy-republish.
// ---------------------------------------------------------------------------
__global__ __launch_bounds__(512, 4) void scan_pf(const float* __restrict__ scores,
                                                  const int*   __restrict__ maskI,
                                                  u64*         __restrict__ ptF,
                                                  u64*         __restrict__ ptB) {
    const int bid   = blockIdx.x;
    const int g     = bid & 7;
    const int chain = bid >> 3;
    const int b     = chain & 31;
    const bool dirB = (chain >> 5) != 0;
    const int tid   = threadIdx.x;

    __shared__ __align__(16) float sm[2][128 * 33];   // fwd E0 tiles
    __shared__ float pldP[32 * 33];                   // polled state, padded
    __shared__ float Ild[136];                        // intermediate

    const u64 mlo = __ballot(maskI[(tid & 63) * BATCH + b] != 0);
    const u64 mhi = __ballot(maskI[(64 + (tid & 63)) * BATCH + b] != 0);
    auto act_of = [&](int t) {
        return (((t < 64) ? (mlo >> t) : (mhi >> (t - 64))) & 1ULL) != 0ULL;
    };

    u64* const pt = (dirB ? ptB : ptF) + (size_t)b * 2048;
    auto sb = [&](int t) { return scores + ((size_t)t * BATCH + b) * TTT; };

    const int out = tid >> 2, s = tid & 3;

    // md: 2=fused pair, 1=single step (tensor tA), 0=copy
    auto getmode = [&](int p, int& md, int& tA, int& tB) {
        if (!dirB) {
            if (p == 31) { md = act_of(64) ? 1 : 0; tA = 64; tB = 64; return; }
            int t0 = 2 + 2*p, t1 = t0 + 1;
            bool a0 = act_of(t0), a1 = act_of(t1);
            if (a0 && a1)      { md = 2; tA = t0; tB = t1; }
            else if (a0 || a1) { md = 1; tA = a0 ? t0 : t1; tB = tA; }
            else               { md = 0; tA = t0; tB = t1; }
        } else {
            if (p == 31) { md = act_of(65) ? 1 : 0; tA = 65; tB = 65; return; }
            int th = 127 - 2*p, tl = th - 1;
            bool ah = act_of(th), al = act_of(tl);
            if (ah && al)      { md = 2; tA = th; tB = tl; }
            else if (ah || al) { md = 1; tA = ah ? th : tl; tB = tA; }
            else               { md = 0; tA = th; tB = tl; }
        }
    };

    // full-state poll: 2 words/thread, per-wave detect, write padded LDS copy
    auto poll = [&](int p) {
        const u64* src = pt + (size_t)(p & 1) * 1024;
        const int x0 = 2 * tid;
        u64 a0v, a1v; bool d0 = false, d1 = false;
        for (;;) {
            if (!d0) { a0v = ald64(src + x0);     d0 = pt_tag(a0v) == p; }
            if (!d1) { a1v = ald64(src + x0 + 1); d1 = pt_tag(a1v) == p; }
            if (__all(d0 && d1)) break;
        }
        const int u = x0 >> 5, v = x0 & 31;
        pldP[u*33 + v]     = pt_val(a0v);
        pldP[u*33 + v + 1] = pt_val(a1v);
    };

    if (!dirB) {
        // ------------------------------ FORWARD ------------------------------
        const int il = tid >> 5;         // loader: i (0..15; +16 second)
        const int jl = tid & 31;         // loader: j
        const size_t e0off = (size_t)il * TT + jl * T + 4 * g;
        const int j1 = out >> 2, kq1 = out & 3;     // phase1 out (j, k')
        const int kq2 = out >> 5, l2 = out & 31;    // phase2 out (k', l)

        float4 c0, c1;
        auto issueE0 = [&](int t) {
            const float* p = sb(t) + e0off;
            c0 = *(const float4*)p;
            c1 = *(const float4*)(p + 16 * TT);
        };
        auto scat = [&](int buf) {
            #pragma unroll
            for (int q = 0; q < 4; ++q) {
                sm[buf][(jl*4 + q)*33 + il]      = (&c0.x)[q];
                sm[buf][(jl*4 + q)*33 + il + 16] = (&c1.x)[q];
            }
        };
        float e1r[8];
        auto issueE1 = [&](int t) {
            const float* p = sb(t) + (size_t)(8*s) * TT + (4*g + kq2) * T + l2;
            #pragma unroll
            for (int q = 0; q < 8; ++q) e1r[q] = p[(size_t)q * TT];
        };

        int md, tA, tB;
        getmode(0, md, tA, tB);
        issueE0(tA); scat(0);
        { int m2, a2, b2; getmode(1, m2, a2, b2); issueE0(a2); }
        __syncthreads();

        for (int p = 0; p < NHOP; ++p) {
            getmode(p, md, tA, tB);
            if (p + 1 < NHOP) scat((p + 1) & 1);     // tile for hop p+1
            if (p + 2 < NHOP) { int m2, a2, b2; getmode(p + 2, m2, a2, b2); issueE0(a2); }
            issueE1(tB);
            poll(p);
            BLOCK_SYNC();   // B1: pldP + tile buf(p&1) ready; certifies reads
            u64* dst = pt + (size_t)((p + 1) & 1) * 1024;
            const int tg2 = p + 1;
            if (md != 0) {
                const float* row = &sm[p & 1][out * 33 + 8 * s];
                float acc = 0.f;
                #pragma unroll
                for (int q = 0; q < 8; ++q)
                    acc = fmaf(exp2f(fmaf(row[q], LOG2E, -OFF4)),
                               pldP[(8*s + q)*33 + j1], acc);
                acc += __shfl_xor(acc, 1, 64);
                acc += __shfl_xor(acc, 2, 64);
                if (s == 0) {
                    if (md == 1) ast64(dst + j1*32 + 4*g + kq1, pt_pack(tg2, acc));
                    else         Ild[out] = acc;
                }
            } else {
                if (s == 0)
                    ast64(dst + (4*g + kq2)*32 + l2,
                          pt_pack(tg2, pldP[(4*g + kq2)*33 + l2]));
            }
            BLOCK_SYNC();   // B2: Ild ready
            if (md == 2) {
                float acc = 0.f;
                #pragma unroll
                for (int q = 0; q < 8; ++q)
                    acc = fmaf(exp2f(fmaf(e1r[q], LOG2E, -OFF4)),
                               Ild[(8*s + q)*4 + kq2], acc);
                acc += __shfl_xor(acc, 1, 64);
                acc += __shfl_xor(acc, 2, 64);
                if (s == 0) ast64(dst + (4*g + kq2)*32 + l2, pt_pack(tg2, acc));
            }
        }
    } else {
        // ------------------------------ BACKWARD ------------------------------
        const int i1 = out >> 5, jj = out & 31;     // phase1 out (i', j)
        const int h2 = out & 31, iq2 = out >> 5;    // phase2 out (h, i')
        float4 rh0, rh1, rl0, rl1;
        auto issueEh = [&](int t) {
            const float* p = sb(t) + (size_t)(4*g + i1) * TT + jj * T + 8 * s;
            rh0 = *(const float4*)p; rh1 = *(const float4*)(p + 4);
        };
        auto issueEl = [&](int t) {
            const float* p = sb(t) + (size_t)h2 * TT + (4*g + iq2) * T + 8 * s;
            rl0 = *(const float4*)p; rl1 = *(const float4*)(p + 4);
        };

        for (int p = 0; p < NHOP; ++p) {
            int md, tA, tB;
            getmode(p, md, tA, tB);
            issueEh(tA); issueEl(tB);
            poll(p);
            BLOCK_SYNC();   // B1
            u64* dst = pt + (size_t)((p + 1) & 1) * 1024;
            const int tg2 = p + 1;
            if (md != 0) {
                const float* pv = &pldP[jj*33 + 8*s];
                float acc;
                acc = exp2f(fmaf(rh0.x, LOG2E, -OFF4)) * pv[0];
                acc = fmaf(exp2f(fmaf(rh0.y, LOG2E, -OFF4)), pv[1], acc);
                acc = fmaf(exp2f(fmaf(rh0.z, LOG2E, -OFF4)), pv[2], acc);
                acc = fmaf(exp2f(fmaf(rh0.w, LOG2E, -OFF4)), pv[3], acc);
                acc = fmaf(exp2f(fmaf(rh1.x, LOG2E, -OFF4)), pv[4], acc);
                acc = fmaf(exp2f(fmaf(rh1.y, LOG2E, -OFF4)), pv[5], acc);
                acc = fmaf(exp2f(fmaf(rh1.z, LOG2E, -OFF4)), pv[6], acc);
                acc = fmaf(exp2f(fmaf(rh1.w, LOG2E, -OFF4)), pv[7], acc);
                acc += __shfl_xor(acc, 1, 64);
                acc += __shfl_xor(acc, 2, 64);
                if (s == 0) {
                    if (md == 1) ast64(dst + (4*g + i1)*32 + jj, pt_pack(tg2, acc));
                    else         Ild[i1*33 + jj] = acc;
                }
            } else {
                if (s == 0)
                    ast64(dst + h2*32 + 4*g + iq2,
                          pt_pack(tg2, pldP[h2*33 + 4*g + iq2]));
            }
            BLOCK_SYNC();   // B2
            if (md == 2) {
                const float* iv = &Ild[iq2*33 + 8*s];
                float acc;
                acc = exp2f(fmaf(rl0.x, LOG2E, -OFF4)) * iv[0];
                acc = fmaf(exp2f(fmaf(rl0.y, LOG2E, -OFF4)), iv[1], acc);
                acc = fmaf(exp2f(fmaf(rl0.z, LOG2E, -OFF4)), iv[2], acc);
                acc = fmaf(exp2f(fmaf(rl0.w, LOG2E, -OFF4)), iv[3], acc);
                acc = fmaf(exp2f(fmaf(rl1.x, LOG2E, -OFF4)), iv[4], acc);
                acc = fmaf(exp2f(fmaf(rl1.y, LOG2E, -OFF4)), iv[5], acc);
                acc = fmaf(exp2f(fmaf(rl1.z, LOG2E, -OFF4)), iv[6], acc);
                acc = fmaf(exp2f(fmaf(rl1.w, LOG2E, -OFF4)), iv[7], acc);
                acc += __shfl_xor(acc, 1, 64);
                acc += __shfl_xor(acc, 2, 64);
                if (s == 0) ast64(dst + h2*32 + 4*g + iq2, pt_pack(tg2, acc));
            }
        }
    }
}

// ---------------------------------------------------------------------------
// Kernel 4: finalize. Q_64, R_64 both tag 32, parity 0, first-major ->
// z_b = 4*cnt_b + log( sum_w Q_64[w]*R_64[w] ).
// ---------------------------------------------------------------------------
__global__ __launch_bounds__(1024) void finalize_pf(const float* __restrict__ ws,
                                                    const u64*  __restrict__ ptF,
                                                    const u64*  __restrict__ ptB,
                                                    const int*  __restrict__ mask,
                                                    float*      __restrict__ out) {
    __shared__ float zs[32];
    const int w = threadIdx.x >> 6, lane = threadIdx.x & 63;
    for (int rep = 0; rep < 2; ++rep) {
        const int b = w + rep * 16;
        const u64* qf = ptF + (size_t)b * 2048;   // parity0
        const u64* rb = ptB + (size_t)b * 2048;   // parity0
        float dot = 0.f;
        #pragma unroll
        for (int e = 0; e < 16; ++e) {
            const int x = lane + 64 * e;
            dot += pt_val(qf[x]) * pt_val(rb[x]);
        }
        float cnt = 0.f;
        {
            int t = 2 + lane;
            if (t < SEQ_LEN) cnt += (mask[t*BATCH + b] != 0) ? 1.f : 0.f;
            t += 64;
            if (t < SEQ_LEN) cnt += (mask[t*BATCH + b] != 0) ? 1.f : 0.f;
        }
        #pragma unroll
        for (int off = 32; off > 0; off >>= 1) {
            dot += __shfl_xor(dot, off, 64);
            cnt += __shfl_xor(cnt, off, 64);
        }
        if (lane == 0) zs[b] = 4.0f * cnt + logf(dot);
    }
    __syncthreads();
    if (threadIdx.x == 0) {
        float tg = 0.f, z = 0.f;
        #pragma unroll
        for (int i = 0; i < 16; ++i) tg += ws[i];
        #pragma unroll
        for (int i = 0; i < 32; ++i) z += zs[i];
        out[0] = (z - tg) / (float)BATCH;
    }
}

// ---------------------------------------------------------------------------
// Fallback (small ws): round-5 single-block-per-batch scan.
// ---------------------------------------------------------------------------
__global__ __launch_bounds__(1024) void scan_fast(const float* __restrict__ scores,
                                                  const int*   __restrict__ maskI,
                                                  float*       __restrict__ ws) {
    const int b    = blockIdx.x;
    const int tid  = threadIdx.x;
    const int w    = tid >> 6;
    const int lane = tid & 63;
    const int h    = lane >> 4;
    const int jp   = (lane >> 3) & 1;
    const int k4   = lane & 7;
    const int j    = w * 2 + jp;

    __shared__ float Q[2][TT];
    __shared__ int   lmask[SEQ_LEN];
    if (tid < SEQ_LEN) lmask[tid] = maskI[tid * BATCH + b];
    {
        int x = tid >> 5, y = tid & 31;
        float p1 = scores[(size_t)(0*BATCH + b)*TTT + START*TT + START*T + x];
        float s1 = scores[(size_t)(1*BATCH + b)*TTT + START*TT + x*T + y];
        Q[1][x*T + y] = __expf(p1 + s1);
    }
    __syncthreads();
    const int loff = h*8*TT + j*T + k4*4;
    float4 SA[8], SB[8];
    auto issue = [&](float4 (&S)[8], int t) {
        const float* p = scores + ((size_t)t*BATCH + b)*TTT + loff;
        #pragma unroll
        for (int m = 0; m < 8; ++m) S[m] = *(const float4*)(p + m*TT);
    };
    auto process = [&](float4 (&S)[8], int t) {
        const float* qc = Q[(t-1) & 1];
        float*       qn = Q[t & 1];
        #pragma unroll
        for (int m = 0; m < 8; ++m) {
            S[m].x = exp2f(fmaf(S[m].x, LOG2E, -OFF4));
            S[m].y = exp2f(fmaf(S[m].y, LOG2E, -OFF4));
            S[m].z = exp2f(fmaf(S[m].z, LOG2E, -OFF4));
            S[m].w = exp2f(fmaf(S[m].w, LOG2E, -OFF4));
        }
        float4 acc = make_float4(0.f, 0.f, 0.f, 0.f);
        #pragma unroll
        for (int m = 0; m < 8; ++m) {
            float q = qc[(h*8 + m)*T + j];
            acc.x = fmaf(S[m].x, q, acc.x);
            acc.y = fmaf(S[m].y, q, acc.y);
            acc.z = fmaf(S[m].z, q, acc.z);
            acc.w = fmaf(S[m].w, q, acc.w);
        }
        acc.x += __shfl_xor(acc.x, 16, 64); acc.y += __shfl_xor(acc.y, 16, 64);
        acc.z += __shfl_xor(acc.z, 16, 64); acc.w += __shfl_xor(acc.w, 16, 64);
        acc.x += __shfl_xor(acc.x, 32, 64); acc.y += __shfl_xor(acc.y, 32, 64);
        acc.z += __shfl_xor(acc.z, 32, 64); acc.w += __shfl_xor(acc.w, 32, 64);
        if (lane < 16) {
            if (lmask[t] != 0) *(float4*)&qn[j*T + k4*4] = acc;
            else               *(float4*)&qn[j*T + k4*4] = *(const float4*)&qc[j*T + k4*4];
        }
        asm volatile("s_waitcnt lgkmcnt(0)" ::: "memory");
        __builtin_amdgcn_s_barrier();
    };
    issue(SA, 2);
    for (int t = 2; t < SEQ_LEN; t += 2) {
        issue(SB, t + 1);
        process(SA, t);
        if (t + 2 < SEQ_LEN) issue(SA, t + 2);
        process(SB, t + 1);
    }
    if (tid == 0) {
        int cnt = 0;
        for (int t = 2; t < SEQ_LEN; ++t) cnt += (lmask[t] != 0);
        ws[16 + b] = 4.0f * (float)cnt + logf(Q[1][END*T + END]);
    }
}

__global__ void finalize_simple(const float* __restrict__ ws, float* __restrict__ out) {
    if (threadIdx.x == 0) {
        float tg = 0.f, z = 0.f;
        #pragma unroll
        for (int i = 0; i < 16; ++i) tg += ws[i];
        #pragma unroll
        for (int i = 0; i < 32; ++i) z += ws[16 + i];
        out[0] = (z - tg) / (float)BATCH;
    }
}

extern "C" void kernel_launch(void* const* d_in, const int* in_sizes, int n_in,
                              void* d_out, int out_size, void* d_ws, size_t ws_size,
                              hipStream_t stream) {
    const float* scores = (const float*)d_in[0];
    const int*   target = (const int*)d_in[1];
    const int*   mask   = (const int*)d_in[2];
    float* out = (float*)d_out;
    float* ws  = (float*)d_ws;
    u64*   ptF = (u64*)((char*)d_ws + 1024);
    u64*   ptB = ptF + (size_t)BATCH * 2048;
    const size_t need = 1024 + (size_t)2 * BATCH * 2048 * sizeof(u64);   // ~1.05 MB

    tg_kernel<<<16, 256, 0, stream>>>(scores, target, mask, ws);
    if (ws_size >= need) {
        init_pf<<<2*BATCH, 256, 0, stream>>>(scores, ptF, ptB);
        scan_pf<<<512, 512, 0, stream>>>(scores, mask, ptF, ptB);
        finalize_pf<<<1, 1024, 0, stream>>>(ws, ptF, ptB, mask, out);
    } else {
        scan_fast<<<BATCH, 1024, 0, stream>>>(scores, mask, ws);
        finalize_simple<<<1, 64, 0, stream>>>(ws, out);
    }
}